// Round 1
// baseline (2005.898 us; speedup 1.0000x reference)
//
#include <hip/hip_runtime.h>
#include <hip/hip_bf16.h>

#define DD 128

__device__ __forceinline__ float sigmoidf_(float v){ return 1.f/(1.f+__expf(-v)); }

// ---------- weight prep: transpose + k4-interleave ----------
// Wt_ih/Wt_hh layout: elem (k,j) at ((k>>2)*384 + j)*4 + (k&3)   (j in [0,384), k in [0,128))
// Wt_dec layout:      elem (k,j) at ((k>>2)*64  + j)*4 + (k&3)   (j in [0,64),  k in [0,128))
__global__ void k_prep(const float* __restrict__ W_ih, const float* __restrict__ W_hh,
                       const float* __restrict__ W_dec,
                       float* __restrict__ Wt_ih, float* __restrict__ Wt_hh,
                       float* __restrict__ Wt_dec){
  int idx = blockIdx.x*256 + threadIdx.x;
  if (idx < 384*128){
    int j = idx / 128, k = idx % 128;
    int o = ((k>>2)*384 + j)*4 + (k&3);
    Wt_ih[o] = W_ih[idx];
    Wt_hh[o] = W_hh[idx];
  } else if (idx < 384*128 + 64*128){
    int t = idx - 384*128;
    int j = t / 128, k = t % 128;
    int o = ((k>>2)*64 + j)*4 + (k&3);
    Wt_dec[o] = W_dec[t];
  }
}

// ---------- encoder: h0 = x @ W_enc^T, accumulate column stats ----------
__global__ void __launch_bounds__(128) k_enc(const float* __restrict__ x,
                        const float* __restrict__ W_enc,
                        float* __restrict__ h0, float* __restrict__ stats, int N){
  const int f = threadIdx.x;
  const float w0 = W_enc[f*3], w1 = W_enc[f*3+1], w2 = W_enc[f*3+2];
  const int chunk = (N + gridDim.x - 1) / gridDim.x;
  const int n0 = blockIdx.x * chunk;
  const int n1 = (n0 + chunk < N) ? (n0 + chunk) : N;
  float s = 0.f, q = 0.f;
  for (int n = n0; n < n1; n++){
    float x0 = x[n*3], x1 = x[n*3+1], x2 = x[n*3+2];
    float h = x0*w0 + x1*w1 + x2*w2;
    h0[(size_t)n*DD + f] = h;
    s += h; q += h*h;
  }
  atomicAdd(&stats[f], s);
  atomicAdd(&stats[DD+f], q);
}

__global__ void k_enc_apply(const float* __restrict__ h0, const float* __restrict__ gamma,
                            const float* __restrict__ beta, const float* __restrict__ stats,
                            float* __restrict__ prev_h, float* __restrict__ h_sum, int N){
  int idx = blockIdx.x*256 + threadIdx.x;
  if (idx >= N*DD) return;
  int f = idx & (DD-1);
  float invN = 1.f / (float)N;
  float mu = stats[f] * invN;
  float var = stats[DD+f] * invN - mu*mu;
  float v = (h0[idx] - mu) * rsqrtf(var + 1e-5f) * gamma[f] + beta[f];
  v = fmaxf(v, 0.f);
  prev_h[idx] = v;
  h_sum[idx]  = v;
}

// ---------- CSR build ----------
__global__ void k_hist(const int* __restrict__ dst, int* __restrict__ counts, int E){
  int e = blockIdx.x*256 + threadIdx.x;
  if (e < E) atomicAdd(&counts[dst[e]], 1);
}

__global__ void __launch_bounds__(1024) k_scan(int* __restrict__ counts /*in counts, out cursors*/,
                                               int* __restrict__ offsets, int N){
  __shared__ int buf[1024];
  __shared__ int carry;
  const int t = threadIdx.x;
  if (t == 0) carry = 0;
  __syncthreads();
  for (int base = 0; base < N; base += 1024){
    int i = base + t;
    int v = (i < N) ? counts[i] : 0;
    buf[t] = v;
    __syncthreads();
    for (int off = 1; off < 1024; off <<= 1){
      int add = (t >= off) ? buf[t-off] : 0;
      __syncthreads();
      buf[t] += add;
      __syncthreads();
    }
    int excl = carry + buf[t] - v;
    if (i < N){ offsets[i] = excl; counts[i] = excl; }
    __syncthreads();
    if (t == 1023) carry += buf[1023];
    __syncthreads();
  }
  if (t == 0) offsets[N] = carry;
}

__global__ void k_fill(const int* __restrict__ src, const int* __restrict__ dst,
                       const float* __restrict__ norm, int* __restrict__ cursors,
                       int* __restrict__ csr_src, float* __restrict__ csr_norm, int E){
  int e = blockIdx.x*256 + threadIdx.x;
  if (e >= E) return;
  int p = atomicAdd(&cursors[dst[e]], 1);
  csr_src[p] = src[e];
  csr_norm[p] = norm[e];
}

// ---------- per-layer aggregation: h_agg[n] = sum_e norm_e * prev_h[src_e]; h_sum += ----------
__global__ void __launch_bounds__(128) k_agg(const float* __restrict__ prev_h,
    const int* __restrict__ offsets, const int* __restrict__ csr_src,
    const float* __restrict__ csr_norm, float* __restrict__ h_agg,
    float* __restrict__ h_sum){
  const int n = blockIdx.x;
  const int f = threadIdx.x;
  const int s0 = offsets[n], s1 = offsets[n+1];
  float acc = 0.f;
  for (int i = s0; i < s1; i++){
    int s = csr_src[i];
    float w = csr_norm[i];
    acc += w * prev_h[(size_t)s*DD + f];
  }
  size_t o = (size_t)n*DD + f;
  h_agg[o] = acc;
  h_sum[o] += acc;
}

// ---------- fused GRU: gi = h_agg@W_ih^T+b_ih, gh = prev_h@W_hh^T+b_hh, gates, update ----------
// 384 threads (thread = output row j), 16 nodes/block.
__global__ void __launch_bounds__(384) k_gru(const float* __restrict__ h_agg,
        float* __restrict__ prev_h,
        const float* __restrict__ Wt_ih, const float* __restrict__ Wt_hh,
        const float* __restrict__ b_ih, const float* __restrict__ b_hh, int N){
  const int j  = threadIdx.x;
  const int n0 = blockIdx.x * 16;
  __shared__ float rz[16][256];
  __shared__ float ph_s[16][DD];

  for (int idx = j; idx < 16*DD; idx += 384){
    int m = idx >> 7, k = idx & (DD-1);
    int nm = n0 + m; if (nm >= N) nm = N-1;
    ph_s[m][k] = prev_h[(size_t)nm*DD + k];
  }
  __syncthreads();

  float si[16], sh[16];
  const float bi = b_ih[j], bh = b_hh[j];
  #pragma unroll
  for (int m = 0; m < 16; m++){ si[m] = bi; sh[m] = bh; }

  const float* arow[16];
  #pragma unroll
  for (int m = 0; m < 16; m++){
    int nm = n0 + m; if (nm >= N) nm = N-1;
    arow[m] = h_agg + (size_t)nm*DD;
  }

  for (int k4 = 0; k4 < 32; k4++){
    float4 wi = *(const float4*)(Wt_ih + ((size_t)k4*384 + j)*4);
    float4 wh = *(const float4*)(Wt_hh + ((size_t)k4*384 + j)*4);
    #pragma unroll
    for (int m = 0; m < 16; m++){
      float4 a = *(const float4*)(arow[m] + k4*4);
      si[m] += a.x*wi.x + a.y*wi.y + a.z*wi.z + a.w*wi.w;
      float4 p = *(const float4*)(&ph_s[m][k4*4]);
      sh[m] += p.x*wh.x + p.y*wh.y + p.z*wh.z + p.w*wh.w;
    }
  }

  if (j < 256){
    #pragma unroll
    for (int m = 0; m < 16; m++) rz[m][j] = sigmoidf_(si[m] + sh[m]);
  }
  __syncthreads();
  if (j >= 256){
    const int f = j - 256;
    #pragma unroll
    for (int m = 0; m < 16; m++){
      int nm = n0 + m;
      if (nm < N){
        float r = rz[m][f], z = rz[m][128+f];
        float nn = tanhf(si[m] + r*sh[m]);
        float hp = ph_s[m][f];
        prev_h[(size_t)nm*DD + f] = (1.f - z)*nn + z*hp;
      }
    }
  }
}

// ---------- decoder stage 1: y1 = (h_sum/6) @ W_dec^T, accumulate column stats ----------
__global__ void __launch_bounds__(256) k_dec1(const float* __restrict__ h_sum,
        const float* __restrict__ Wt_dec, float* __restrict__ y1,
        float* __restrict__ stats_d, int N){
  const int j = threadIdx.x & 63;
  const int slot = threadIdx.x >> 6;
  float s = 0.f, q = 0.f;
  for (int n = blockIdx.x*4 + slot; n < N; n += gridDim.x*4){
    float acc = 0.f;
    for (int k = 0; k < DD; k += 4){
      float4 zv = *(const float4*)(h_sum + (size_t)n*DD + k);
      float4 wv = *(const float4*)(Wt_dec + ((size_t)(k>>2)*64 + j)*4);
      acc += zv.x*wv.x + zv.y*wv.y + zv.z*wv.z + zv.w*wv.w;
    }
    acc *= (1.f/6.f);
    y1[(size_t)n*64 + j] = acc;
    s += acc; q += acc*acc;
  }
  __shared__ float red[2][4][64];
  red[0][slot][j] = s; red[1][slot][j] = q;
  __syncthreads();
  if (slot == 0){
    s = red[0][0][j] + red[0][1][j] + red[0][2][j] + red[0][3][j];
    q = red[1][0][j] + red[1][1][j] + red[1][2][j] + red[1][3][j];
    atomicAdd(&stats_d[j], s);
    atomicAdd(&stats_d[64+j], q);
  }
}

// ---------- decoder stage 2: bn + relu + dot with W_dec2 ----------
__global__ void __launch_bounds__(256) k_dec2(const float* __restrict__ y1,
        const float* __restrict__ gamma, const float* __restrict__ beta,
        const float* __restrict__ W_dec2, const float* __restrict__ stats_d,
        float* __restrict__ out, int N){
  const int j = threadIdx.x & 63;
  const int g = threadIdx.x >> 6;
  const int n = blockIdx.x*4 + g;
  if (n >= N) return;
  float invN = 1.f / (float)N;
  float mu = stats_d[j] * invN;
  float var = stats_d[64+j] * invN - mu*mu;
  float v = (y1[(size_t)n*64 + j] - mu) * rsqrtf(var + 1e-5f) * gamma[j] + beta[j];
  v = fmaxf(v, 0.f) * W_dec2[j];
  for (int off = 32; off > 0; off >>= 1) v += __shfl_down(v, off, 64);
  if (j == 0) out[n] = v;
}

extern "C" void kernel_launch(void* const* d_in, const int* in_sizes, int n_in,
                              void* d_out, int out_size, void* d_ws, size_t ws_size,
                              hipStream_t stream) {
  const int N = in_sizes[0] / 3;
  const int E = in_sizes[1] / 2;

  const float* x     = (const float*)d_in[0];
  const int*   ei    = (const int*)d_in[1];
  const int*   src   = ei;
  const int*   dst   = ei + E;
  const float* norm  = (const float*)d_in[2];
  const float* W_enc = (const float*)d_in[3];
  const float* g_e   = (const float*)d_in[4];
  const float* b_e   = (const float*)d_in[5];
  const float* W_ih  = (const float*)d_in[6];
  const float* W_hh  = (const float*)d_in[7];
  const float* b_ih  = (const float*)d_in[8];
  const float* b_hh  = (const float*)d_in[9];
  const float* W_dec = (const float*)d_in[10];
  const float* g_d   = (const float*)d_in[11];
  const float* b_d   = (const float*)d_in[12];
  const float* W_dec2= (const float*)d_in[13];
  float* out = (float*)d_out;

  float* ws = (float*)d_ws;
  const size_t NF = (size_t)N * DD;
  float* prev_h = ws;
  float* h_sum  = ws + NF;
  float* h_agg  = ws + 2*NF;          // also h0 tmp and y1 (N*64) reuse
  float* stats  = ws + 3*NF;          // 384 floats: [0:256) enc, [256:384) dec
  float* Wt_ih  = stats + 384;
  float* Wt_hh  = Wt_ih + 384*128;
  float* Wt_dec = Wt_hh + 384*128;
  int*   offsets = (int*)(Wt_dec + 64*128);   // N+1
  int*   cursors = offsets + N + 1;           // N (doubles as counts)
  int*   csr_src = cursors + N;               // E
  float* csr_norm = (float*)(csr_src + E);    // E

  hipMemsetAsync(stats, 0, 384*sizeof(float), stream);
  hipMemsetAsync(cursors, 0, (size_t)N*sizeof(int), stream);

  k_prep<<<(384*128 + 64*128 + 255)/256, 256, 0, stream>>>(W_ih, W_hh, W_dec, Wt_ih, Wt_hh, Wt_dec);
  k_enc<<<256, 128, 0, stream>>>(x, W_enc, h_agg /*h0 tmp*/, stats, N);
  k_enc_apply<<<(N*DD + 255)/256, 256, 0, stream>>>(h_agg, g_e, b_e, stats, prev_h, h_sum, N);

  k_hist<<<(E + 255)/256, 256, 0, stream>>>(dst, cursors, E);
  k_scan<<<1, 1024, 0, stream>>>(cursors, offsets, N);
  k_fill<<<(E + 255)/256, 256, 0, stream>>>(src, dst, norm, cursors, csr_src, csr_norm, E);

  for (int l = 0; l < 5; l++){
    k_agg<<<N, 128, 0, stream>>>(prev_h, offsets, csr_src, csr_norm, h_agg, h_sum);
    k_gru<<<(N + 15)/16, 384, 0, stream>>>(h_agg, prev_h, Wt_ih, Wt_hh, b_ih, b_hh, N);
  }

  k_dec1<<<256, 256, 0, stream>>>(h_sum, Wt_dec, h_agg /*y1*/, stats + 256, N);
  k_dec2<<<(N + 3)/4, 256, 0, stream>>>(h_agg, g_d, b_d, W_dec2, stats + 256, out, N);
}

// Round 2
// 1240.671 us; speedup vs baseline: 1.6168x; 1.6168x over previous
//
#include <hip/hip_runtime.h>
#include <hip/hip_bf16.h>

#define DD 128

typedef short bf16x8 __attribute__((ext_vector_type(8)));
typedef float f32x4 __attribute__((ext_vector_type(4)));

__device__ __forceinline__ float sigmoidf_(float v){ return 1.f/(1.f+__expf(-v)); }

__device__ __forceinline__ void bsplit(float v, unsigned short& hi, unsigned short& lo){
  __hip_bfloat16 h = __float2bfloat16(v);
  float hf = __bfloat162float(h);
  __hip_bfloat16 l = __float2bfloat16(v - hf);
  hi = *(unsigned short*)&h;
  lo = *(unsigned short*)&l;
}

// ---------- weight prep: decoder transpose (fp32) ----------
__global__ void k_prep(const float* __restrict__ W_dec, float* __restrict__ Wt_dec){
  int idx = blockIdx.x*256 + threadIdx.x;
  if (idx < 64*128){
    int j = idx / 128, k = idx % 128;
    int o = ((k>>2)*64 + j)*4 + (k&3);
    Wt_dec[o] = W_dec[idx];
  }
}

// ---------- weight prep: GRU weights -> bf16 hi/lo in B-fragment order ----------
// frag index fi for (nt,ks,l,t): fi = (((nt*4+ks)*64)+l)*8 + t
// maps to W[j][k] with j = nt*16 + (l&15), k = ks*32 + ((l>>4)&3)*8 + t
__global__ void k_prep_frag(const float* __restrict__ W_ih, const float* __restrict__ W_hh,
                            unsigned short* __restrict__ Wih_hi, unsigned short* __restrict__ Wih_lo,
                            unsigned short* __restrict__ Whh_hi, unsigned short* __restrict__ Whh_lo){
  int idx = blockIdx.x*256 + threadIdx.x;
  const int TOT = 384*128;
  if (idx >= 2*TOT) return;
  const float* W = (idx < TOT) ? W_ih : W_hh;
  unsigned short* Dh = (idx < TOT) ? Wih_hi : Whh_hi;
  unsigned short* Dl = (idx < TOT) ? Wih_lo : Whh_lo;
  int fi = (idx < TOT) ? idx : idx - TOT;
  int t = fi & 7;
  int l = (fi >> 3) & 63;
  int ksnt = fi >> 9;
  int ks = ksnt & 3, nt = ksnt >> 2;
  int j = nt*16 + (l & 15);
  int k = ks*32 + ((l >> 4) & 3)*8 + t;
  unsigned short hi, lo;
  bsplit(W[j*128 + k], hi, lo);
  Dh[fi] = hi; Dl[fi] = lo;
}

// ---------- encoder: h0 = x @ W_enc^T, accumulate column stats ----------
__global__ void __launch_bounds__(128) k_enc(const float* __restrict__ x,
                        const float* __restrict__ W_enc,
                        float* __restrict__ h0, float* __restrict__ stats, int N){
  const int f = threadIdx.x;
  const float w0 = W_enc[f*3], w1 = W_enc[f*3+1], w2 = W_enc[f*3+2];
  const int chunk = (N + gridDim.x - 1) / gridDim.x;
  const int n0 = blockIdx.x * chunk;
  const int n1 = (n0 + chunk < N) ? (n0 + chunk) : N;
  float s = 0.f, q = 0.f;
  for (int n = n0; n < n1; n++){
    float x0 = x[n*3], x1 = x[n*3+1], x2 = x[n*3+2];
    float h = x0*w0 + x1*w1 + x2*w2;
    h0[(size_t)n*DD + f] = h;
    s += h; q += h*h;
  }
  atomicAdd(&stats[f], s);
  atomicAdd(&stats[DD+f], q);
}

__global__ void k_enc_apply(const float* __restrict__ h0, const float* __restrict__ gamma,
                            const float* __restrict__ beta, const float* __restrict__ stats,
                            float* __restrict__ prev_h, float* __restrict__ h_sum,
                            unsigned short* __restrict__ ph_hi, unsigned short* __restrict__ ph_lo, int N){
  int idx = blockIdx.x*256 + threadIdx.x;
  if (idx >= N*DD) return;
  int f = idx & (DD-1);
  float invN = 1.f / (float)N;
  float mu = stats[f] * invN;
  float var = stats[DD+f] * invN - mu*mu;
  float v = (h0[idx] - mu) * rsqrtf(var + 1e-5f) * gamma[f] + beta[f];
  v = fmaxf(v, 0.f);
  prev_h[idx] = v;
  h_sum[idx]  = v;
  unsigned short hi, lo; bsplit(v, hi, lo);
  ph_hi[idx] = hi; ph_lo[idx] = lo;
}

// ---------- CSR build ----------
__global__ void k_hist(const int* __restrict__ dst, int* __restrict__ counts, int E){
  int e = blockIdx.x*256 + threadIdx.x;
  if (e < E) atomicAdd(&counts[dst[e]], 1);
}

__global__ void __launch_bounds__(1024) k_scan(int* __restrict__ counts,
                                               int* __restrict__ offsets, int N){
  __shared__ int buf[1024];
  __shared__ int carry;
  const int t = threadIdx.x;
  if (t == 0) carry = 0;
  __syncthreads();
  for (int base = 0; base < N; base += 1024){
    int i = base + t;
    int v = (i < N) ? counts[i] : 0;
    buf[t] = v;
    __syncthreads();
    for (int off = 1; off < 1024; off <<= 1){
      int add = (t >= off) ? buf[t-off] : 0;
      __syncthreads();
      buf[t] += add;
      __syncthreads();
    }
    int excl = carry + buf[t] - v;
    if (i < N){ offsets[i] = excl; counts[i] = excl; }
    __syncthreads();
    if (t == 1023) carry += buf[1023];
    __syncthreads();
  }
  if (t == 0) offsets[N] = carry;
}

__global__ void k_fill(const int* __restrict__ src, const int* __restrict__ dst,
                       const float* __restrict__ norm, int* __restrict__ cursors,
                       int* __restrict__ csr_src, float* __restrict__ csr_norm, int E){
  int e = blockIdx.x*256 + threadIdx.x;
  if (e >= E) return;
  int p = atomicAdd(&cursors[dst[e]], 1);
  csr_src[p] = src[e];
  csr_norm[p] = norm[e];
}

// ---------- aggregation: h_agg[n] = sum_e norm_e * prev_h[src_e]; h_sum +=; emit bf16 hi/lo ----------
__global__ void __launch_bounds__(128) k_agg(const float* __restrict__ prev_h,
    const int* __restrict__ offsets, const int* __restrict__ csr_src,
    const float* __restrict__ csr_norm,
    unsigned short* __restrict__ agg_hi, unsigned short* __restrict__ agg_lo,
    float* __restrict__ h_sum){
  const int n = blockIdx.x;
  const int f = threadIdx.x;
  const int s0 = offsets[n], s1 = offsets[n+1];
  float acc = 0.f;
  for (int i = s0; i < s1; i++){
    int s = csr_src[i];
    float w = csr_norm[i];
    acc += w * prev_h[(size_t)s*DD + f];
  }
  size_t o = (size_t)n*DD + f;
  h_sum[o] += acc;
  unsigned short hi, lo; bsplit(acc, hi, lo);
  agg_hi[o] = hi; agg_lo[o] = lo;
}

// ---------- fused GRU via bf16 MFMA (hi/lo split, 3 terms = fp32-like accuracy) ----------
// Block: 16 nodes x 384 outputs. 512 threads = 8 waves; wave w owns N-tiles w*3..w*3+2.
// mfma_f32_16x16x32_bf16: A[m=lane&15][k=(lane>>4)*8+t]; C: col=lane&15,row=(lane>>4)*4+reg.
#define LPAD 388
__global__ void __launch_bounds__(512) k_gru_mfma(
        const unsigned short* __restrict__ agg_hi, const unsigned short* __restrict__ agg_lo,
        unsigned short* __restrict__ ph_hi, unsigned short* __restrict__ ph_lo,
        float* __restrict__ prev_h,
        const unsigned short* __restrict__ Wih_hi, const unsigned short* __restrict__ Wih_lo,
        const unsigned short* __restrict__ Whh_hi, const unsigned short* __restrict__ Whh_lo,
        const float* __restrict__ b_ih, const float* __restrict__ b_hh, int N){
  __shared__ float lgi[16][LPAD];
  __shared__ float lgh[16][LPAD];
  const int tid = threadIdx.x;
  const int w = tid >> 6;       // wave 0..7
  const int l = tid & 63;       // lane
  const int n0 = blockIdx.x * 16;
  const int arow = l & 15;      // A-frag row (node within tile)
  const int aq   = l >> 4;      // quad

  f32x4 acc_i[3], acc_h[3];
  #pragma unroll
  for (int t = 0; t < 3; t++){
    acc_i[t] = (f32x4){0.f,0.f,0.f,0.f};
    acc_h[t] = (f32x4){0.f,0.f,0.f,0.f};
  }

  const size_t abase = (size_t)(n0 + arow)*DD + aq*8;
  #pragma unroll
  for (int ks = 0; ks < 4; ks++){
    bf16x8 aih = *(const bf16x8*)(agg_hi + abase + ks*32);
    bf16x8 ail = *(const bf16x8*)(agg_lo + abase + ks*32);
    bf16x8 aph = *(const bf16x8*)(ph_hi  + abase + ks*32);
    bf16x8 apl = *(const bf16x8*)(ph_lo  + abase + ks*32);
    #pragma unroll
    for (int t = 0; t < 3; t++){
      int nt = w*3 + t;
      size_t bo = ((size_t)(nt*4 + ks)*64 + l)*8;
      bf16x8 bih = *(const bf16x8*)(Wih_hi + bo);
      bf16x8 bil = *(const bf16x8*)(Wih_lo + bo);
      bf16x8 bhh = *(const bf16x8*)(Whh_hi + bo);
      bf16x8 bhl = *(const bf16x8*)(Whh_lo + bo);
      acc_i[t] = __builtin_amdgcn_mfma_f32_16x16x32_bf16(aih, bih, acc_i[t], 0, 0, 0);
      acc_i[t] = __builtin_amdgcn_mfma_f32_16x16x32_bf16(aih, bil, acc_i[t], 0, 0, 0);
      acc_i[t] = __builtin_amdgcn_mfma_f32_16x16x32_bf16(ail, bih, acc_i[t], 0, 0, 0);
      acc_h[t] = __builtin_amdgcn_mfma_f32_16x16x32_bf16(aph, bhh, acc_h[t], 0, 0, 0);
      acc_h[t] = __builtin_amdgcn_mfma_f32_16x16x32_bf16(aph, bhl, acc_h[t], 0, 0, 0);
      acc_h[t] = __builtin_amdgcn_mfma_f32_16x16x32_bf16(apl, bhh, acc_h[t], 0, 0, 0);
    }
  }

  // C-layout -> LDS (+bias). row = aq*4+r, col j = nt*16 + (l&15).
  #pragma unroll
  for (int t = 0; t < 3; t++){
    int nt = w*3 + t;
    int j = nt*16 + (l & 15);
    float bi = b_ih[j], bh = b_hh[j];
    int r0 = aq*4;
    #pragma unroll
    for (int r = 0; r < 4; r++){
      lgi[r0+r][j] = acc_i[t][r] + bi;
      lgh[r0+r][j] = acc_h[t][r] + bh;
    }
  }
  __syncthreads();

  // gate phase: 16 nodes x 128 features = 2048 elems, 4 per thread
  #pragma unroll
  for (int it = 0; it < 4; it++){
    int idx = tid + it*512;
    int m = idx >> 7, f = idx & 127;
    int n = n0 + m;
    if (n < N){
      float sir = lgi[m][f],      shr = lgh[m][f];
      float siz = lgi[m][128+f],  shz = lgh[m][128+f];
      float sin_ = lgi[m][256+f], shn = lgh[m][256+f];
      float r = sigmoidf_(sir + shr);
      float z = sigmoidf_(siz + shz);
      float nn = tanhf(sin_ + r*shn);
      size_t o = (size_t)n*DD + f;
      float hp = prev_h[o];
      float h = (1.f - z)*nn + z*hp;
      prev_h[o] = h;
      unsigned short hi, lo; bsplit(h, hi, lo);
      ph_hi[o] = hi; ph_lo[o] = lo;
    }
  }
}

// ---------- decoder stage 1 ----------
__global__ void __launch_bounds__(256) k_dec1(const float* __restrict__ h_sum,
        const float* __restrict__ Wt_dec, float* __restrict__ y1,
        float* __restrict__ stats_d, int N){
  const int j = threadIdx.x & 63;
  const int slot = threadIdx.x >> 6;
  float s = 0.f, q = 0.f;
  for (int n = blockIdx.x*4 + slot; n < N; n += gridDim.x*4){
    float acc = 0.f;
    for (int k = 0; k < DD; k += 4){
      float4 zv = *(const float4*)(h_sum + (size_t)n*DD + k);
      float4 wv = *(const float4*)(Wt_dec + ((size_t)(k>>2)*64 + j)*4);
      acc += zv.x*wv.x + zv.y*wv.y + zv.z*wv.z + zv.w*wv.w;
    }
    acc *= (1.f/6.f);
    y1[(size_t)n*64 + j] = acc;
    s += acc; q += acc*acc;
  }
  __shared__ float red[2][4][64];
  red[0][slot][j] = s; red[1][slot][j] = q;
  __syncthreads();
  if (slot == 0){
    s = red[0][0][j] + red[0][1][j] + red[0][2][j] + red[0][3][j];
    q = red[1][0][j] + red[1][1][j] + red[1][2][j] + red[1][3][j];
    atomicAdd(&stats_d[j], s);
    atomicAdd(&stats_d[64+j], q);
  }
}

// ---------- decoder stage 2 ----------
__global__ void __launch_bounds__(256) k_dec2(const float* __restrict__ y1,
        const float* __restrict__ gamma, const float* __restrict__ beta,
        const float* __restrict__ W_dec2, const float* __restrict__ stats_d,
        float* __restrict__ out, int N){
  const int j = threadIdx.x & 63;
  const int g = threadIdx.x >> 6;
  const int n = blockIdx.x*4 + g;
  if (n >= N) return;
  float invN = 1.f / (float)N;
  float mu = stats_d[j] * invN;
  float var = stats_d[64+j] * invN - mu*mu;
  float v = (y1[(size_t)n*64 + j] - mu) * rsqrtf(var + 1e-5f) * gamma[j] + beta[j];
  v = fmaxf(v, 0.f) * W_dec2[j];
  for (int off = 32; off > 0; off >>= 1) v += __shfl_down(v, off, 64);
  if (j == 0) out[n] = v;
}

extern "C" void kernel_launch(void* const* d_in, const int* in_sizes, int n_in,
                              void* d_out, int out_size, void* d_ws, size_t ws_size,
                              hipStream_t stream) {
  const int N = in_sizes[0] / 3;
  const int E = in_sizes[1] / 2;

  const float* x     = (const float*)d_in[0];
  const int*   ei    = (const int*)d_in[1];
  const int*   src   = ei;
  const int*   dst   = ei + E;
  const float* norm  = (const float*)d_in[2];
  const float* W_enc = (const float*)d_in[3];
  const float* g_e   = (const float*)d_in[4];
  const float* b_e   = (const float*)d_in[5];
  const float* W_ih  = (const float*)d_in[6];
  const float* W_hh  = (const float*)d_in[7];
  const float* b_ih  = (const float*)d_in[8];
  const float* b_hh  = (const float*)d_in[9];
  const float* W_dec = (const float*)d_in[10];
  const float* g_d   = (const float*)d_in[11];
  const float* b_d   = (const float*)d_in[12];
  const float* W_dec2= (const float*)d_in[13];
  float* out = (float*)d_out;

  float* ws = (float*)d_ws;
  const size_t NF = (size_t)N * DD;          // 6.4M
  float* prev_h = ws;                        // NF
  float* h_sum  = prev_h + NF;               // NF
  float* stats  = h_sum + NF;                // 384
  float* Wt_dec = stats + 384;               // 64*128
  unsigned short* Wih_hi = (unsigned short*)(Wt_dec + 64*128);  // 384*128 each
  unsigned short* Wih_lo = Wih_hi + 384*128;
  unsigned short* Whh_hi = Wih_lo + 384*128;
  unsigned short* Whh_lo = Whh_hi + 384*128;
  unsigned short* agg_hi = Whh_lo + 384*128; // NF ushorts
  unsigned short* agg_lo = agg_hi + NF;      // NF ushorts
  unsigned short* ph_hi  = agg_lo + NF;      // NF ushorts
  unsigned short* ph_lo  = ph_hi + NF;       // NF ushorts
  int*   offsets = (int*)(ph_lo + NF);       // N+1
  int*   cursors = offsets + N + 1;          // N
  int*   csr_src = cursors + N;              // E
  float* csr_norm = (float*)(csr_src + E);   // E
  float* h0 = (float*)agg_hi;                // N*128 fp32 tmp (spans agg_hi+agg_lo)
  float* y1 = (float*)agg_hi;                // N*64 fp32 (decoder, agg arrays dead)

  hipMemsetAsync(stats, 0, 384*sizeof(float), stream);
  hipMemsetAsync(cursors, 0, (size_t)N*sizeof(int), stream);

  k_prep<<<(64*128 + 255)/256, 256, 0, stream>>>(W_dec, Wt_dec);
  k_prep_frag<<<(2*384*128 + 255)/256, 256, 0, stream>>>(W_ih, W_hh, Wih_hi, Wih_lo, Whh_hi, Whh_lo);
  k_enc<<<256, 128, 0, stream>>>(x, W_enc, h0, stats, N);
  k_enc_apply<<<(N*DD + 255)/256, 256, 0, stream>>>(h0, g_e, b_e, stats, prev_h, h_sum, ph_hi, ph_lo, N);

  k_hist<<<(E + 255)/256, 256, 0, stream>>>(dst, cursors, E);
  k_scan<<<1, 1024, 0, stream>>>(cursors, offsets, N);
  k_fill<<<(E + 255)/256, 256, 0, stream>>>(src, dst, norm, cursors, csr_src, csr_norm, E);

  for (int l = 0; l < 5; l++){
    k_agg<<<N, 128, 0, stream>>>(prev_h, offsets, csr_src, csr_norm, agg_hi, agg_lo, h_sum);
    k_gru_mfma<<<(N + 15)/16, 512, 0, stream>>>(agg_hi, agg_lo, ph_hi, ph_lo, prev_h,
                                                Wih_hi, Wih_lo, Whh_hi, Whh_lo, b_ih, b_hh, N);
  }

  k_dec1<<<256, 256, 0, stream>>>(h_sum, Wt_dec, y1, stats + 256, N);
  k_dec2<<<(N + 3)/4, 256, 0, stream>>>(y1, g_d, b_d, W_dec2, stats + 256, out, N);
}

// Round 3
// 968.636 us; speedup vs baseline: 2.0708x; 1.2808x over previous
//
#include <hip/hip_runtime.h>
#include <hip/hip_bf16.h>

#define DD 128

typedef short bf16x8 __attribute__((ext_vector_type(8)));
typedef float f32x4 __attribute__((ext_vector_type(4)));

__device__ __forceinline__ float sigmoidf_(float v){ return 1.f/(1.f+__expf(-v)); }
__device__ __forceinline__ float tanhf_(float v){
  float e2 = __expf(2.f*v);
  return 1.f - 2.f/(e2 + 1.f);   // safe: v->+inf => 1, v->-inf => -1
}

__device__ __forceinline__ void bsplit(float v, unsigned short& hi, unsigned short& lo){
  __hip_bfloat16 h = __float2bfloat16(v);
  float hf = __bfloat162float(h);
  __hip_bfloat16 l = __float2bfloat16(v - hf);
  hi = *(unsigned short*)&h;
  lo = *(unsigned short*)&l;
}

// ---------- weight prep: decoder transpose (fp32) ----------
__global__ void k_prep(const float* __restrict__ W_dec, float* __restrict__ Wt_dec){
  int idx = blockIdx.x*256 + threadIdx.x;
  if (idx < 64*128){
    int j = idx / 128, k = idx % 128;
    int o = ((k>>2)*64 + j)*4 + (k&3);
    Wt_dec[o] = W_dec[idx];
  }
}

// ---------- weight prep: GRU weights -> bf16 hi/lo in B-fragment order ----------
// Tile nt in [0,24): fg = nt/3, gate = nt%3. Column j = gate*128 + fg*16 + (l&15).
// frag index fi = (((nt*4+ks)*64)+l)*8 + t ; k = ks*32 + ((l>>4)&3)*8 + t
__global__ void k_prep_frag(const float* __restrict__ W_ih, const float* __restrict__ W_hh,
                            unsigned short* __restrict__ Wih_hi, unsigned short* __restrict__ Wih_lo,
                            unsigned short* __restrict__ Whh_hi, unsigned short* __restrict__ Whh_lo){
  int idx = blockIdx.x*256 + threadIdx.x;
  const int TOT = 384*128;
  if (idx >= 2*TOT) return;
  const float* W = (idx < TOT) ? W_ih : W_hh;
  unsigned short* Dh = (idx < TOT) ? Wih_hi : Whh_hi;
  unsigned short* Dl = (idx < TOT) ? Wih_lo : Whh_lo;
  int fi = (idx < TOT) ? idx : idx - TOT;
  int t = fi & 7;
  int l = (fi >> 3) & 63;
  int ks = (fi >> 9) & 3;
  int nt = fi >> 11;
  int fg = nt / 3, gate = nt % 3;
  int j = gate*128 + fg*16 + (l & 15);
  int k = ks*32 + ((l >> 4) & 3)*8 + t;
  unsigned short hi, lo;
  bsplit(W[j*128 + k], hi, lo);
  Dh[fi] = hi; Dl[fi] = lo;
}

// ---------- encoder ----------
__global__ void __launch_bounds__(128) k_enc(const float* __restrict__ x,
                        const float* __restrict__ W_enc,
                        float* __restrict__ h0, float* __restrict__ stats, int N){
  const int f = threadIdx.x;
  const float w0 = W_enc[f*3], w1 = W_enc[f*3+1], w2 = W_enc[f*3+2];
  const int chunk = (N + gridDim.x - 1) / gridDim.x;
  const int n0 = blockIdx.x * chunk;
  const int n1 = (n0 + chunk < N) ? (n0 + chunk) : N;
  float s = 0.f, q = 0.f;
  for (int n = n0; n < n1; n++){
    float x0 = x[n*3], x1 = x[n*3+1], x2 = x[n*3+2];
    float h = x0*w0 + x1*w1 + x2*w2;
    h0[(size_t)n*DD + f] = h;
    s += h; q += h*h;
  }
  atomicAdd(&stats[f], s);
  atomicAdd(&stats[DD+f], q);
}

__global__ void k_enc_apply(const float* __restrict__ h0, const float* __restrict__ gamma,
                            const float* __restrict__ beta, const float* __restrict__ stats,
                            float* __restrict__ prev_h, float* __restrict__ h_sum,
                            unsigned short* __restrict__ ph_hi, unsigned short* __restrict__ ph_lo, int N){
  int idx = blockIdx.x*256 + threadIdx.x;
  if (idx >= N*DD) return;
  int f = idx & (DD-1);
  float invN = 1.f / (float)N;
  float mu = stats[f] * invN;
  float var = stats[DD+f] * invN - mu*mu;
  float v = (h0[idx] - mu) * rsqrtf(var + 1e-5f) * gamma[f] + beta[f];
  v = fmaxf(v, 0.f);
  prev_h[idx] = v;
  h_sum[idx]  = v;
  unsigned short hi, lo; bsplit(v, hi, lo);
  ph_hi[idx] = hi; ph_lo[idx] = lo;
}

// ---------- CSR build ----------
__global__ void k_hist(const int* __restrict__ dst, int* __restrict__ counts, int E){
  int e = blockIdx.x*256 + threadIdx.x;
  if (e < E) atomicAdd(&counts[dst[e]], 1);
}

__global__ void __launch_bounds__(256) k_scan_part(const int* __restrict__ counts,
                                                   int* __restrict__ partials, int N){
  int i = blockIdx.x*256 + threadIdx.x;
  int v = (i < N) ? counts[i] : 0;
  #pragma unroll
  for (int off = 32; off > 0; off >>= 1) v += __shfl_down(v, off, 64);
  __shared__ int red[4];
  if ((threadIdx.x & 63) == 0) red[threadIdx.x >> 6] = v;
  __syncthreads();
  if (threadIdx.x == 0) partials[blockIdx.x] = red[0]+red[1]+red[2]+red[3];
}

__global__ void __launch_bounds__(256) k_scan_mid(int* __restrict__ partials, int P,
                                                  int* __restrict__ offsets, int N){
  __shared__ int lds[4];
  __shared__ int carry_s;
  const int lane = threadIdx.x & 63, wid = threadIdx.x >> 6;
  if (threadIdx.x == 0) carry_s = 0;
  __syncthreads();
  for (int base = 0; base < P; base += 256){
    int i = base + threadIdx.x;
    int v = (i < P) ? partials[i] : 0;
    int orig = v;
    #pragma unroll
    for (int off = 1; off < 64; off <<= 1){
      int u = __shfl_up(v, off, 64);
      if (lane >= off) v += u;
    }
    if (lane == 63) lds[wid] = v;
    __syncthreads();
    if (threadIdx.x == 0){
      int s = carry_s;
      for (int k = 0; k < 4; k++){ int t = lds[k]; lds[k] = s; s += t; }
      carry_s = s;
    }
    __syncthreads();
    int excl = v - orig + lds[wid];
    if (i < P) partials[i] = excl;
    __syncthreads();
  }
  if (threadIdx.x == 0) offsets[N] = carry_s;
}

__global__ void __launch_bounds__(256) k_scan_expand(const int* __restrict__ counts,
        const int* __restrict__ partials, int* __restrict__ offsets,
        int* __restrict__ cursors, int N){
  int i = blockIdx.x*256 + threadIdx.x;
  int v = (i < N) ? counts[i] : 0;
  int orig = v;
  const int lane = threadIdx.x & 63, wid = threadIdx.x >> 6;
  #pragma unroll
  for (int off = 1; off < 64; off <<= 1){
    int u = __shfl_up(v, off, 64);
    if (lane >= off) v += u;
  }
  __shared__ int lds[4];
  if (lane == 63) lds[wid] = v;
  __syncthreads();
  int wbase = 0;
  for (int k = 0; k < wid; k++) wbase += lds[k];
  int excl = partials[blockIdx.x] + wbase + v - orig;
  if (i < N){ offsets[i] = excl; cursors[i] = excl; }
}

__global__ void k_fill(const int* __restrict__ src, const int* __restrict__ dst,
                       const float* __restrict__ norm, int* __restrict__ cursors,
                       int* __restrict__ csr_src, float* __restrict__ csr_norm, int E){
  int e = blockIdx.x*256 + threadIdx.x;
  if (e >= E) return;
  int p = atomicAdd(&cursors[dst[e]], 1);
  csr_src[p] = src[e];
  csr_norm[p] = norm[e];
}

// ---------- aggregation: half-wave (32 lanes x float4) per node, 4-deep edge unroll ----------
__global__ void __launch_bounds__(256) k_agg(const float* __restrict__ prev_h,
    const int* __restrict__ offsets, const int* __restrict__ csr_src,
    const float* __restrict__ csr_norm,
    unsigned short* __restrict__ agg_hi, unsigned short* __restrict__ agg_lo,
    float* __restrict__ h_sum, int N){
  const int half = threadIdx.x >> 5;   // node slot 0..7
  const int q    = threadIdx.x & 31;   // feature quad
  const int n = blockIdx.x*8 + half;
  if (n >= N) return;
  const int s0 = offsets[n], s1 = offsets[n+1];
  float ax=0.f, ay=0.f, az=0.f, aw=0.f;
  int i = s0;
  for (; i + 4 <= s1; i += 4){
    int sA = csr_src[i],   sB = csr_src[i+1], sC = csr_src[i+2], sD = csr_src[i+3];
    float wA = csr_norm[i],   wB = csr_norm[i+1], wC = csr_norm[i+2], wD = csr_norm[i+3];
    float4 A = *(const float4*)(prev_h + (size_t)sA*DD + q*4);
    float4 B = *(const float4*)(prev_h + (size_t)sB*DD + q*4);
    float4 C = *(const float4*)(prev_h + (size_t)sC*DD + q*4);
    float4 D = *(const float4*)(prev_h + (size_t)sD*DD + q*4);
    ax = fmaf(wA,A.x,ax); ay = fmaf(wA,A.y,ay); az = fmaf(wA,A.z,az); aw = fmaf(wA,A.w,aw);
    ax = fmaf(wB,B.x,ax); ay = fmaf(wB,B.y,ay); az = fmaf(wB,B.z,az); aw = fmaf(wB,B.w,aw);
    ax = fmaf(wC,C.x,ax); ay = fmaf(wC,C.y,ay); az = fmaf(wC,C.z,az); aw = fmaf(wC,C.w,aw);
    ax = fmaf(wD,D.x,ax); ay = fmaf(wD,D.y,ay); az = fmaf(wD,D.z,az); aw = fmaf(wD,D.w,aw);
  }
  for (; i < s1; i++){
    int s = csr_src[i];
    float w = csr_norm[i];
    float4 A = *(const float4*)(prev_h + (size_t)s*DD + q*4);
    ax = fmaf(w,A.x,ax); ay = fmaf(w,A.y,ay); az = fmaf(w,A.z,az); aw = fmaf(w,A.w,aw);
  }
  size_t o = (size_t)n*DD + q*4;
  float4 hs = *(const float4*)(h_sum + o);
  hs.x += ax; hs.y += ay; hs.z += az; hs.w += aw;
  *(float4*)(h_sum + o) = hs;
  ushort4 vhi, vlo;
  bsplit(ax, vhi.x, vlo.x); bsplit(ay, vhi.y, vlo.y);
  bsplit(az, vhi.z, vlo.z); bsplit(aw, vhi.w, vlo.w);
  *(ushort4*)(agg_hi + o) = vhi;
  *(ushort4*)(agg_lo + o) = vlo;
}

// ---------- fused GRU via bf16 MFMA, register-resident gates ----------
// Block: 32 nodes (two 16-row A tiles), 512 threads = 8 waves.
// Wave w owns feature group fg=w: tiles nt=w*3+{0,1,2} = gates {r,z,n} for cols f=w*16..w*16+15.
// C layout: row(node-in-tile) = (l>>4)*4+reg, col = l&15.
__global__ void __launch_bounds__(512) k_gru_mfma(
        const unsigned short* __restrict__ agg_hi, const unsigned short* __restrict__ agg_lo,
        unsigned short* __restrict__ ph_hi, unsigned short* __restrict__ ph_lo,
        float* __restrict__ prev_h,
        const unsigned short* __restrict__ Wih_hi, const unsigned short* __restrict__ Wih_lo,
        const unsigned short* __restrict__ Whh_hi, const unsigned short* __restrict__ Whh_lo,
        const float* __restrict__ b_ih, const float* __restrict__ b_hh, int N){
  const int tid = threadIdx.x;
  const int w = tid >> 6;
  const int l = tid & 63;
  const int n0 = blockIdx.x * 32;
  const int ar = l & 15;
  const int aq = l >> 4;

  f32x4 acc_i[2][3], acc_h[2][3];
  #pragma unroll
  for (int ta = 0; ta < 2; ta++)
    #pragma unroll
    for (int t = 0; t < 3; t++){
      acc_i[ta][t] = (f32x4){0.f,0.f,0.f,0.f};
      acc_h[ta][t] = (f32x4){0.f,0.f,0.f,0.f};
    }

  int r0 = n0 + ar;      if (r0 >= N) r0 = N-1;
  int r1 = n0 + 16 + ar; if (r1 >= N) r1 = N-1;
  const size_t a0 = (size_t)r0*DD + aq*8;
  const size_t a1 = (size_t)r1*DD + aq*8;

  #pragma unroll
  for (int ks = 0; ks < 4; ks++){
    bf16x8 ih0 = *(const bf16x8*)(agg_hi + a0 + ks*32);
    bf16x8 ih1 = *(const bf16x8*)(agg_hi + a1 + ks*32);
    bf16x8 il0 = *(const bf16x8*)(agg_lo + a0 + ks*32);
    bf16x8 il1 = *(const bf16x8*)(agg_lo + a1 + ks*32);
    bf16x8 hh0 = *(const bf16x8*)(ph_hi  + a0 + ks*32);
    bf16x8 hh1 = *(const bf16x8*)(ph_hi  + a1 + ks*32);
    bf16x8 hl0 = *(const bf16x8*)(ph_lo  + a0 + ks*32);
    bf16x8 hl1 = *(const bf16x8*)(ph_lo  + a1 + ks*32);
    #pragma unroll
    for (int t = 0; t < 3; t++){
      size_t bo = ((size_t)((w*3 + t)*4 + ks)*64 + l)*8;
      bf16x8 bih = *(const bf16x8*)(Wih_hi + bo);
      bf16x8 bil = *(const bf16x8*)(Wih_lo + bo);
      bf16x8 bhh = *(const bf16x8*)(Whh_hi + bo);
      bf16x8 bhl = *(const bf16x8*)(Whh_lo + bo);
      acc_i[0][t] = __builtin_amdgcn_mfma_f32_16x16x32_bf16(ih0, bih, acc_i[0][t], 0, 0, 0);
      acc_i[0][t] = __builtin_amdgcn_mfma_f32_16x16x32_bf16(ih0, bil, acc_i[0][t], 0, 0, 0);
      acc_i[0][t] = __builtin_amdgcn_mfma_f32_16x16x32_bf16(il0, bih, acc_i[0][t], 0, 0, 0);
      acc_i[1][t] = __builtin_amdgcn_mfma_f32_16x16x32_bf16(ih1, bih, acc_i[1][t], 0, 0, 0);
      acc_i[1][t] = __builtin_amdgcn_mfma_f32_16x16x32_bf16(ih1, bil, acc_i[1][t], 0, 0, 0);
      acc_i[1][t] = __builtin_amdgcn_mfma_f32_16x16x32_bf16(il1, bih, acc_i[1][t], 0, 0, 0);
      acc_h[0][t] = __builtin_amdgcn_mfma_f32_16x16x32_bf16(hh0, bhh, acc_h[0][t], 0, 0, 0);
      acc_h[0][t] = __builtin_amdgcn_mfma_f32_16x16x32_bf16(hh0, bhl, acc_h[0][t], 0, 0, 0);
      acc_h[0][t] = __builtin_amdgcn_mfma_f32_16x16x32_bf16(hl0, bhh, acc_h[0][t], 0, 0, 0);
      acc_h[1][t] = __builtin_amdgcn_mfma_f32_16x16x32_bf16(hh1, bhh, acc_h[1][t], 0, 0, 0);
      acc_h[1][t] = __builtin_amdgcn_mfma_f32_16x16x32_bf16(hh1, bhl, acc_h[1][t], 0, 0, 0);
      acc_h[1][t] = __builtin_amdgcn_mfma_f32_16x16x32_bf16(hl1, bhh, acc_h[1][t], 0, 0, 0);
    }
  }

  // all reads of ph_hi/ph_lo (A-frags) must complete before any wave overwrites them
  __syncthreads();

  const int f = w*16 + ar;
  const float bir = b_ih[f], biz = b_ih[128+f], bin_ = b_ih[256+f];
  const float bhr = b_hh[f], bhz = b_hh[128+f], bhn = b_hh[256+f];
  #pragma unroll
  for (int ta = 0; ta < 2; ta++){
    #pragma unroll
    for (int r = 0; r < 4; r++){
      int n = n0 + ta*16 + aq*4 + r;
      if (n < N){
        float sir = acc_i[ta][0][r] + bir, shr = acc_h[ta][0][r] + bhr;
        float siz = acc_i[ta][1][r] + biz, shz = acc_h[ta][1][r] + bhz;
        float sin_ = acc_i[ta][2][r] + bin_, shn = acc_h[ta][2][r] + bhn;
        float rr = sigmoidf_(sir + shr);
        float zz = sigmoidf_(siz + shz);
        float nn = tanhf_(sin_ + rr*shn);
        size_t o = (size_t)n*DD + f;
        float hp = prev_h[o];
        float h = (1.f - zz)*nn + zz*hp;
        prev_h[o] = h;
        unsigned short hi, lo; bsplit(h, hi, lo);
        ph_hi[o] = hi; ph_lo[o] = lo;
      }
    }
  }
}

// ---------- decoder stage 1 ----------
__global__ void __launch_bounds__(256) k_dec1(const float* __restrict__ h_sum,
        const float* __restrict__ Wt_dec, float* __restrict__ y1,
        float* __restrict__ stats_d, int N){
  const int j = threadIdx.x & 63;
  const int slot = threadIdx.x >> 6;
  float s = 0.f, q = 0.f;
  for (int n = blockIdx.x*4 + slot; n < N; n += gridDim.x*4){
    float acc = 0.f;
    for (int k = 0; k < DD; k += 4){
      float4 zv = *(const float4*)(h_sum + (size_t)n*DD + k);
      float4 wv = *(const float4*)(Wt_dec + ((size_t)(k>>2)*64 + j)*4);
      acc += zv.x*wv.x + zv.y*wv.y + zv.z*wv.z + zv.w*wv.w;
    }
    acc *= (1.f/6.f);
    y1[(size_t)n*64 + j] = acc;
    s += acc; q += acc*acc;
  }
  __shared__ float red[2][4][64];
  red[0][slot][j] = s; red[1][slot][j] = q;
  __syncthreads();
  if (slot == 0){
    s = red[0][0][j] + red[0][1][j] + red[0][2][j] + red[0][3][j];
    q = red[1][0][j] + red[1][1][j] + red[1][2][j] + red[1][3][j];
    atomicAdd(&stats_d[j], s);
    atomicAdd(&stats_d[64+j], q);
  }
}

// ---------- decoder stage 2 ----------
__global__ void __launch_bounds__(256) k_dec2(const float* __restrict__ y1,
        const float* __restrict__ gamma, const float* __restrict__ beta,
        const float* __restrict__ W_dec2, const float* __restrict__ stats_d,
        float* __restrict__ out, int N){
  const int j = threadIdx.x & 63;
  const int g = threadIdx.x >> 6;
  const int n = blockIdx.x*4 + g;
  if (n >= N) return;
  float invN = 1.f / (float)N;
  float mu = stats_d[j] * invN;
  float var = stats_d[64+j] * invN - mu*mu;
  float v = (y1[(size_t)n*64 + j] - mu) * rsqrtf(var + 1e-5f) * gamma[j] + beta[j];
  v = fmaxf(v, 0.f) * W_dec2[j];
  for (int off = 32; off > 0; off >>= 1) v += __shfl_down(v, off, 64);
  if (j == 0) out[n] = v;
}

extern "C" void kernel_launch(void* const* d_in, const int* in_sizes, int n_in,
                              void* d_out, int out_size, void* d_ws, size_t ws_size,
                              hipStream_t stream) {
  const int N = in_sizes[0] / 3;
  const int E = in_sizes[1] / 2;
  const int P = (N + 255) / 256;

  const float* x     = (const float*)d_in[0];
  const int*   ei    = (const int*)d_in[1];
  const int*   src   = ei;
  const int*   dst   = ei + E;
  const float* norm  = (const float*)d_in[2];
  const float* W_enc = (const float*)d_in[3];
  const float* g_e   = (const float*)d_in[4];
  const float* b_e   = (const float*)d_in[5];
  const float* W_ih  = (const float*)d_in[6];
  const float* W_hh  = (const float*)d_in[7];
  const float* b_ih  = (const float*)d_in[8];
  const float* b_hh  = (const float*)d_in[9];
  const float* W_dec = (const float*)d_in[10];
  const float* g_d   = (const float*)d_in[11];
  const float* b_d   = (const float*)d_in[12];
  const float* W_dec2= (const float*)d_in[13];
  float* out = (float*)d_out;

  float* ws = (float*)d_ws;
  const size_t NF = (size_t)N * DD;
  float* prev_h = ws;                        // NF
  float* h_sum  = prev_h + NF;               // NF
  float* stats  = h_sum + NF;                // 384
  float* Wt_dec = stats + 384;               // 64*128
  unsigned short* Wih_hi = (unsigned short*)(Wt_dec + 64*128);
  unsigned short* Wih_lo = Wih_hi + 384*128;
  unsigned short* Whh_hi = Wih_lo + 384*128;
  unsigned short* Whh_lo = Whh_hi + 384*128;
  unsigned short* agg_hi = Whh_lo + 384*128; // NF ushorts
  unsigned short* agg_lo = agg_hi + NF;
  unsigned short* ph_hi  = agg_lo + NF;
  unsigned short* ph_lo  = ph_hi + NF;
  int*   counts  = (int*)(ph_lo + NF);       // N
  int*   offsets = counts + N;               // N+1
  int*   cursors = offsets + N + 1;          // N
  int*   partials= cursors + N;              // P
  int*   csr_src = partials + P;             // E
  float* csr_norm = (float*)(csr_src + E);   // E
  float* h0 = (float*)agg_hi;                // N*128 fp32 tmp
  float* y1 = (float*)agg_hi;                // N*64 fp32 (decoder)

  hipMemsetAsync(stats, 0, 384*sizeof(float), stream);
  hipMemsetAsync(counts, 0, (size_t)N*sizeof(int), stream);

  k_prep<<<(64*128 + 255)/256, 256, 0, stream>>>(W_dec, Wt_dec);
  k_prep_frag<<<(2*384*128 + 255)/256, 256, 0, stream>>>(W_ih, W_hh, Wih_hi, Wih_lo, Whh_hi, Whh_lo);
  k_enc<<<256, 128, 0, stream>>>(x, W_enc, h0, stats, N);
  k_enc_apply<<<(N*DD + 255)/256, 256, 0, stream>>>(h0, g_e, b_e, stats, prev_h, h_sum, ph_hi, ph_lo, N);

  k_hist<<<(E + 255)/256, 256, 0, stream>>>(dst, counts, E);
  k_scan_part<<<P, 256, 0, stream>>>(counts, partials, N);
  k_scan_mid<<<1, 256, 0, stream>>>(partials, P, offsets, N);
  k_scan_expand<<<P, 256, 0, stream>>>(counts, partials, offsets, cursors, N);
  k_fill<<<(E + 255)/256, 256, 0, stream>>>(src, dst, norm, cursors, csr_src, csr_norm, E);

  for (int l = 0; l < 5; l++){
    k_agg<<<(N + 7)/8, 256, 0, stream>>>(prev_h, offsets, csr_src, csr_norm, agg_hi, agg_lo, h_sum, N);
    k_gru_mfma<<<(N + 31)/32, 512, 0, stream>>>(agg_hi, agg_lo, ph_hi, ph_lo, prev_h,
                                                Wih_hi, Wih_lo, Whh_hi, Whh_lo, b_ih, b_hh, N);
  }

  k_dec1<<<256, 256, 0, stream>>>(h_sum, Wt_dec, y1, stats + 256, N);
  k_dec2<<<(N + 3)/4, 256, 0, stream>>>(y1, g_d, b_d, W_dec2, stats + 256, out, N);
}

// Round 4
// 878.541 us; speedup vs baseline: 2.2832x; 1.1026x over previous
//
#include <hip/hip_runtime.h>
#include <hip/hip_bf16.h>

#define DD 128

typedef short bf16x8 __attribute__((ext_vector_type(8)));
typedef float f32x4 __attribute__((ext_vector_type(4)));

__device__ __forceinline__ float sigmoidf_(float v){ return 1.f/(1.f+__expf(-v)); }
__device__ __forceinline__ float tanhf_(float v){
  float e2 = __expf(2.f*v);
  return 1.f - 2.f/(e2 + 1.f);
}

__device__ __forceinline__ void bsplit(float v, unsigned short& hi, unsigned short& lo){
  __hip_bfloat16 h = __float2bfloat16(v);
  float hf = __bfloat162float(h);
  __hip_bfloat16 l = __float2bfloat16(v - hf);
  hi = *(unsigned short*)&h;
  lo = *(unsigned short*)&l;
}

// ---------- weight prep: decoder transpose (fp32) ----------
__global__ void k_prep(const float* __restrict__ W_dec, float* __restrict__ Wt_dec){
  int idx = blockIdx.x*256 + threadIdx.x;
  if (idx < 64*128){
    int j = idx / 128, k = idx % 128;
    int o = ((k>>2)*64 + j)*4 + (k&3);
    Wt_dec[o] = W_dec[idx];
  }
}

// ---------- weight prep: GRU weights -> bf16 hi/lo in B-fragment order ----------
// Tile nt in [0,24): fg = nt/3, gate = nt%3. Column j = gate*128 + fg*16 + (l&15).
// frag index fi = (((nt*4+ks)*64)+l)*8 + t ; k = ks*32 + ((l>>4)&3)*8 + t
__global__ void k_prep_frag(const float* __restrict__ W_ih, const float* __restrict__ W_hh,
                            unsigned short* __restrict__ Wih_hi, unsigned short* __restrict__ Wih_lo,
                            unsigned short* __restrict__ Whh_hi, unsigned short* __restrict__ Whh_lo){
  int idx = blockIdx.x*256 + threadIdx.x;
  const int TOT = 384*128;
  if (idx >= 2*TOT) return;
  const float* W = (idx < TOT) ? W_ih : W_hh;
  unsigned short* Dh = (idx < TOT) ? Wih_hi : Whh_hi;
  unsigned short* Dl = (idx < TOT) ? Wih_lo : Whh_lo;
  int fi = (idx < TOT) ? idx : idx - TOT;
  int t = fi & 7;
  int l = (fi >> 3) & 63;
  int ks = (fi >> 9) & 3;
  int nt = fi >> 11;
  int fg = nt / 3, gate = nt % 3;
  int j = gate*128 + fg*16 + (l & 15);
  int k = ks*32 + ((l >> 4) & 3)*8 + t;
  unsigned short hi, lo;
  bsplit(W[j*128 + k], hi, lo);
  Dh[fi] = hi; Dl[fi] = lo;
}

// ---------- encoder ----------
__global__ void __launch_bounds__(128) k_enc(const float* __restrict__ x,
                        const float* __restrict__ W_enc,
                        float* __restrict__ h0, float* __restrict__ stats, int N){
  const int f = threadIdx.x;
  const float w0 = W_enc[f*3], w1 = W_enc[f*3+1], w2 = W_enc[f*3+2];
  const int chunk = (N + gridDim.x - 1) / gridDim.x;
  const int n0 = blockIdx.x * chunk;
  const int n1 = (n0 + chunk < N) ? (n0 + chunk) : N;
  float s = 0.f, q = 0.f;
  for (int n = n0; n < n1; n++){
    float x0 = x[n*3], x1 = x[n*3+1], x2 = x[n*3+2];
    float h = x0*w0 + x1*w1 + x2*w2;
    h0[(size_t)n*DD + f] = h;
    s += h; q += h*h;
  }
  atomicAdd(&stats[f], s);
  atomicAdd(&stats[DD+f], q);
}

__global__ void k_enc_apply(const float* __restrict__ h0, const float* __restrict__ gamma,
                            const float* __restrict__ beta, const float* __restrict__ stats,
                            float* __restrict__ prev_h, float* __restrict__ h_sum,
                            unsigned short* __restrict__ ph_hi, unsigned short* __restrict__ ph_lo, int N){
  int idx = blockIdx.x*256 + threadIdx.x;
  if (idx >= N*DD) return;
  int f = idx & (DD-1);
  float invN = 1.f / (float)N;
  float mu = stats[f] * invN;
  float var = stats[DD+f] * invN - mu*mu;
  float v = (h0[idx] - mu) * rsqrtf(var + 1e-5f) * gamma[f] + beta[f];
  v = fmaxf(v, 0.f);
  prev_h[idx] = v;
  h_sum[idx]  = v;
  unsigned short hi, lo; bsplit(v, hi, lo);
  ph_hi[idx] = hi; ph_lo[idx] = lo;
}

// ---------- CSR build ----------
__global__ void k_hist(const int* __restrict__ dst, int* __restrict__ counts, int E){
  int e = blockIdx.x*256 + threadIdx.x;
  if (e < E) atomicAdd(&counts[dst[e]], 1);
}

__global__ void __launch_bounds__(256) k_scan_part(const int* __restrict__ counts,
                                                   int* __restrict__ partials, int N){
  int i = blockIdx.x*256 + threadIdx.x;
  int v = (i < N) ? counts[i] : 0;
  #pragma unroll
  for (int off = 32; off > 0; off >>= 1) v += __shfl_down(v, off, 64);
  __shared__ int red[4];
  if ((threadIdx.x & 63) == 0) red[threadIdx.x >> 6] = v;
  __syncthreads();
  if (threadIdx.x == 0) partials[blockIdx.x] = red[0]+red[1]+red[2]+red[3];
}

__global__ void __launch_bounds__(256) k_scan_mid(int* __restrict__ partials, int P,
                                                  int* __restrict__ offsets, int N){
  __shared__ int lds[4];
  __shared__ int carry_s;
  const int lane = threadIdx.x & 63, wid = threadIdx.x >> 6;
  if (threadIdx.x == 0) carry_s = 0;
  __syncthreads();
  for (int base = 0; base < P; base += 256){
    int i = base + threadIdx.x;
    int v = (i < P) ? partials[i] : 0;
    int orig = v;
    #pragma unroll
    for (int off = 1; off < 64; off <<= 1){
      int u = __shfl_up(v, off, 64);
      if (lane >= off) v += u;
    }
    if (lane == 63) lds[wid] = v;
    __syncthreads();
    if (threadIdx.x == 0){
      int s = carry_s;
      for (int k = 0; k < 4; k++){ int t = lds[k]; lds[k] = s; s += t; }
      carry_s = s;
    }
    __syncthreads();
    int excl = v - orig + lds[wid];
    if (i < P) partials[i] = excl;
    __syncthreads();
  }
  if (threadIdx.x == 0) offsets[N] = carry_s;
}

__global__ void __launch_bounds__(256) k_scan_expand(const int* __restrict__ counts,
        const int* __restrict__ partials, int* __restrict__ offsets,
        int* __restrict__ cursors, int N){
  int i = blockIdx.x*256 + threadIdx.x;
  int v = (i < N) ? counts[i] : 0;
  int orig = v;
  const int lane = threadIdx.x & 63, wid = threadIdx.x >> 6;
  #pragma unroll
  for (int off = 1; off < 64; off <<= 1){
    int u = __shfl_up(v, off, 64);
    if (lane >= off) v += u;
  }
  __shared__ int lds[4];
  if (lane == 63) lds[wid] = v;
  __syncthreads();
  int wbase = 0;
  for (int k = 0; k < wid; k++) wbase += lds[k];
  int excl = partials[blockIdx.x] + wbase + v - orig;
  if (i < N){ offsets[i] = excl; cursors[i] = excl; }
}

__global__ void k_fill(const int* __restrict__ src, const int* __restrict__ dst,
                       const float* __restrict__ norm, int* __restrict__ cursors,
                       int* __restrict__ csr_src, float* __restrict__ csr_norm, int E){
  int e = blockIdx.x*256 + threadIdx.x;
  if (e >= E) return;
  int p = atomicAdd(&cursors[dst[e]], 1);
  csr_src[p] = src[e];
  csr_norm[p] = norm[e];
}

// ---------- fused layer: gather -> LDS (bf16 hi/lo, xor-swizzled) -> MFMA -> gates ----------
// 512 threads. Phase1: 16 half-waves x 2 passes gather 32 nodes, h_sum RMW fused.
// Phase2: wave w = feature group; tiles {r,z,n}; A(agg) from LDS, A(ph) from global.
// Phase3: register gates; write new h to prev_nxt (double-buffered) + ph hi/lo.
// LDS swizzle: 16B chunk c of row m stored at chunk c^(m&7) -> preserves 16B alignment.
__global__ void __launch_bounds__(512) k_layer(
        const float* __restrict__ prev_cur, float* __restrict__ prev_nxt,
        unsigned short* __restrict__ ph_hi, unsigned short* __restrict__ ph_lo,
        float* __restrict__ h_sum,
        const int* __restrict__ offsets, const int* __restrict__ csr_src,
        const float* __restrict__ csr_norm,
        const unsigned short* __restrict__ Wih_hi, const unsigned short* __restrict__ Wih_lo,
        const unsigned short* __restrict__ Whh_hi, const unsigned short* __restrict__ Whh_lo,
        const float* __restrict__ b_ih, const float* __restrict__ b_hh, int N){
  __shared__ unsigned short s_ah[32*DD];
  __shared__ unsigned short s_al[32*DD];
  const int tid = threadIdx.x;
  const int n0 = blockIdx.x * 32;

  // ---- phase 1: gather ----
  {
    const int hw = tid >> 5;
    const int q  = tid & 31;
    #pragma unroll
    for (int pass = 0; pass < 2; pass++){
      const int m = hw + pass*16;
      const int n = n0 + m;
      float ax=0.f, ay=0.f, az=0.f, aw=0.f;
      if (n < N){
        const int s0 = offsets[n], s1 = offsets[n+1];
        int i = s0;
        for (; i + 4 <= s1; i += 4){
          int sA = csr_src[i],   sB = csr_src[i+1], sC = csr_src[i+2], sD = csr_src[i+3];
          float wA = csr_norm[i],   wB = csr_norm[i+1], wC = csr_norm[i+2], wD = csr_norm[i+3];
          float4 A = *(const float4*)(prev_cur + (size_t)sA*DD + q*4);
          float4 B = *(const float4*)(prev_cur + (size_t)sB*DD + q*4);
          float4 C = *(const float4*)(prev_cur + (size_t)sC*DD + q*4);
          float4 D = *(const float4*)(prev_cur + (size_t)sD*DD + q*4);
          ax = fmaf(wA,A.x,ax); ay = fmaf(wA,A.y,ay); az = fmaf(wA,A.z,az); aw = fmaf(wA,A.w,aw);
          ax = fmaf(wB,B.x,ax); ay = fmaf(wB,B.y,ay); az = fmaf(wB,B.z,az); aw = fmaf(wB,B.w,aw);
          ax = fmaf(wC,C.x,ax); ay = fmaf(wC,C.y,ay); az = fmaf(wC,C.z,az); aw = fmaf(wC,C.w,aw);
          ax = fmaf(wD,D.x,ax); ay = fmaf(wD,D.y,ay); az = fmaf(wD,D.z,az); aw = fmaf(wD,D.w,aw);
        }
        for (; i < s1; i++){
          int s = csr_src[i];
          float w = csr_norm[i];
          float4 A = *(const float4*)(prev_cur + (size_t)s*DD + q*4);
          ax = fmaf(w,A.x,ax); ay = fmaf(w,A.y,ay); az = fmaf(w,A.z,az); aw = fmaf(w,A.w,aw);
        }
        size_t o = (size_t)n*DD + q*4;
        float4 hs = *(const float4*)(h_sum + o);
        hs.x += ax; hs.y += ay; hs.z += az; hs.w += aw;
        *(float4*)(h_sum + o) = hs;
      }
      ushort4 vhi, vlo;
      bsplit(ax, vhi.x, vlo.x); bsplit(ay, vhi.y, vlo.y);
      bsplit(az, vhi.z, vlo.z); bsplit(aw, vhi.w, vlo.w);
      int cc = (q >> 1) ^ (m & 7);
      int off = m*DD + cc*8 + (q & 1)*4;
      *(ushort4*)(s_ah + off) = vhi;
      *(ushort4*)(s_al + off) = vlo;
    }
  }
  __syncthreads();

  // ---- phase 2: MFMA ----
  const int w = tid >> 6, l = tid & 63, ar = l & 15, aq = l >> 4;
  f32x4 acc_i[2][3], acc_h[2][3];
  #pragma unroll
  for (int ta = 0; ta < 2; ta++)
    #pragma unroll
    for (int t = 0; t < 3; t++){
      acc_i[ta][t] = (f32x4){0.f,0.f,0.f,0.f};
      acc_h[ta][t] = (f32x4){0.f,0.f,0.f,0.f};
    }

  int r0 = n0 + ar;      if (r0 >= N) r0 = N-1;
  int r1 = n0 + 16 + ar; if (r1 >= N) r1 = N-1;
  const size_t p0 = (size_t)r0*DD + aq*8;
  const size_t p1 = (size_t)r1*DD + aq*8;
  const int sw = ar & 7;   // swizzle key for rows ar and 16+ar (same low3 bits)

  #pragma unroll
  for (int ks = 0; ks < 4; ks++){
    const int c = (ks*4 + aq) ^ sw;
    bf16x8 ih0 = *(const bf16x8*)(s_ah + ar*DD       + c*8);
    bf16x8 ih1 = *(const bf16x8*)(s_ah + (16+ar)*DD  + c*8);
    bf16x8 il0 = *(const bf16x8*)(s_al + ar*DD       + c*8);
    bf16x8 il1 = *(const bf16x8*)(s_al + (16+ar)*DD  + c*8);
    bf16x8 hh0 = *(const bf16x8*)(ph_hi + p0 + ks*32);
    bf16x8 hh1 = *(const bf16x8*)(ph_hi + p1 + ks*32);
    bf16x8 hl0 = *(const bf16x8*)(ph_lo + p0 + ks*32);
    bf16x8 hl1 = *(const bf16x8*)(ph_lo + p1 + ks*32);
    #pragma unroll
    for (int t = 0; t < 3; t++){
      size_t bo = ((size_t)((w*3 + t)*4 + ks)*64 + l)*8;
      bf16x8 bih = *(const bf16x8*)(Wih_hi + bo);
      bf16x8 bil = *(const bf16x8*)(Wih_lo + bo);
      bf16x8 bhh = *(const bf16x8*)(Whh_hi + bo);
      bf16x8 bhl = *(const bf16x8*)(Whh_lo + bo);
      acc_i[0][t] = __builtin_amdgcn_mfma_f32_16x16x32_bf16(ih0, bih, acc_i[0][t], 0, 0, 0);
      acc_i[0][t] = __builtin_amdgcn_mfma_f32_16x16x32_bf16(ih0, bil, acc_i[0][t], 0, 0, 0);
      acc_i[0][t] = __builtin_amdgcn_mfma_f32_16x16x32_bf16(il0, bih, acc_i[0][t], 0, 0, 0);
      acc_i[1][t] = __builtin_amdgcn_mfma_f32_16x16x32_bf16(ih1, bih, acc_i[1][t], 0, 0, 0);
      acc_i[1][t] = __builtin_amdgcn_mfma_f32_16x16x32_bf16(ih1, bil, acc_i[1][t], 0, 0, 0);
      acc_i[1][t] = __builtin_amdgcn_mfma_f32_16x16x32_bf16(il1, bih, acc_i[1][t], 0, 0, 0);
      acc_h[0][t] = __builtin_amdgcn_mfma_f32_16x16x32_bf16(hh0, bhh, acc_h[0][t], 0, 0, 0);
      acc_h[0][t] = __builtin_amdgcn_mfma_f32_16x16x32_bf16(hh0, bhl, acc_h[0][t], 0, 0, 0);
      acc_h[0][t] = __builtin_amdgcn_mfma_f32_16x16x32_bf16(hl0, bhh, acc_h[0][t], 0, 0, 0);
      acc_h[1][t] = __builtin_amdgcn_mfma_f32_16x16x32_bf16(hh1, bhh, acc_h[1][t], 0, 0, 0);
      acc_h[1][t] = __builtin_amdgcn_mfma_f32_16x16x32_bf16(hh1, bhl, acc_h[1][t], 0, 0, 0);
      acc_h[1][t] = __builtin_amdgcn_mfma_f32_16x16x32_bf16(hl1, bhh, acc_h[1][t], 0, 0, 0);
    }
  }

  // all A-frag reads of ph_hi/ph_lo must complete before epilogue overwrites them
  __syncthreads();

  // ---- phase 3: gates ----
  const int f = w*16 + ar;
  const float bir = b_ih[f], biz = b_ih[128+f], bin_ = b_ih[256+f];
  const float bhr = b_hh[f], bhz = b_hh[128+f], bhn = b_hh[256+f];
  #pragma unroll
  for (int ta = 0; ta < 2; ta++){
    #pragma unroll
    for (int r = 0; r < 4; r++){
      int n = n0 + ta*16 + aq*4 + r;
      if (n < N){
        float sir = acc_i[ta][0][r] + bir, shr = acc_h[ta][0][r] + bhr;
        float siz = acc_i[ta][1][r] + biz, shz = acc_h[ta][1][r] + bhz;
        float sin_ = acc_i[ta][2][r] + bin_, shn = acc_h[ta][2][r] + bhn;
        float rr = sigmoidf_(sir + shr);
        float zz = sigmoidf_(siz + shz);
        float nn = tanhf_(sin_ + rr*shn);
        size_t o = (size_t)n*DD + f;
        float hp = prev_cur[o];
        float h = (1.f - zz)*nn + zz*hp;
        prev_nxt[o] = h;
        unsigned short hi, lo; bsplit(h, hi, lo);
        ph_hi[o] = hi; ph_lo[o] = lo;
      }
    }
  }
}

// ---------- decoder stage 1: 8 split stats copies to cap atomic contention ----------
__global__ void __launch_bounds__(256) k_dec1(const float* __restrict__ h_sum,
        const float* __restrict__ Wt_dec, float* __restrict__ y1,
        float* __restrict__ stats_d, int N){
  const int j = threadIdx.x & 63;
  const int slot = threadIdx.x >> 6;
  float s = 0.f, q = 0.f;
  for (int n = blockIdx.x*4 + slot; n < N; n += gridDim.x*4){
    float acc = 0.f;
    for (int k = 0; k < DD; k += 4){
      float4 zv = *(const float4*)(h_sum + (size_t)n*DD + k);
      float4 wv = *(const float4*)(Wt_dec + ((size_t)(k>>2)*64 + j)*4);
      acc += zv.x*wv.x + zv.y*wv.y + zv.z*wv.z + zv.w*wv.w;
    }
    acc *= (1.f/6.f);
    y1[(size_t)n*64 + j] = acc;
    s += acc; q += acc*acc;
  }
  __shared__ float red[2][4][64];
  red[0][slot][j] = s; red[1][slot][j] = q;
  __syncthreads();
  if (slot == 0){
    s = red[0][0][j] + red[0][1][j] + red[0][2][j] + red[0][3][j];
    q = red[1][0][j] + red[1][1][j] + red[1][2][j] + red[1][3][j];
    float* st = stats_d + (size_t)(blockIdx.x & 7)*128;
    atomicAdd(&st[j], s);
    atomicAdd(&st[64+j], q);
  }
}

// ---------- decoder stage 2: sum stats copies, bn + relu + dot ----------
__global__ void __launch_bounds__(256) k_dec2(const float* __restrict__ y1,
        const float* __restrict__ gamma, const float* __restrict__ beta,
        const float* __restrict__ W_dec2, const float* __restrict__ stats_d,
        float* __restrict__ out, int N){
  const int j = threadIdx.x & 63;
  const int g = threadIdx.x >> 6;
  const int n = blockIdx.x*4 + g;
  if (n >= N) return;
  float ssum = 0.f, qsum = 0.f;
  #pragma unroll
  for (int c = 0; c < 8; c++){
    ssum += stats_d[c*128 + j];
    qsum += stats_d[c*128 + 64 + j];
  }
  float invN = 1.f / (float)N;
  float mu = ssum * invN;
  float var = qsum * invN - mu*mu;
  float v = (y1[(size_t)n*64 + j] - mu) * rsqrtf(var + 1e-5f) * gamma[j] + beta[j];
  v = fmaxf(v, 0.f) * W_dec2[j];
  for (int off = 32; off > 0; off >>= 1) v += __shfl_down(v, off, 64);
  if (j == 0) out[n] = v;
}

extern "C" void kernel_launch(void* const* d_in, const int* in_sizes, int n_in,
                              void* d_out, int out_size, void* d_ws, size_t ws_size,
                              hipStream_t stream) {
  const int N = in_sizes[0] / 3;
  const int E = in_sizes[1] / 2;
  const int P = (N + 255) / 256;

  const float* x     = (const float*)d_in[0];
  const int*   ei    = (const int*)d_in[1];
  const int*   src   = ei;
  const int*   dst   = ei + E;
  const float* norm  = (const float*)d_in[2];
  const float* W_enc = (const float*)d_in[3];
  const float* g_e   = (const float*)d_in[4];
  const float* b_e   = (const float*)d_in[5];
  const float* W_ih  = (const float*)d_in[6];
  const float* W_hh  = (const float*)d_in[7];
  const float* b_ih  = (const float*)d_in[8];
  const float* b_hh  = (const float*)d_in[9];
  const float* W_dec = (const float*)d_in[10];
  const float* g_d   = (const float*)d_in[11];
  const float* b_d   = (const float*)d_in[12];
  const float* W_dec2= (const float*)d_in[13];
  float* out = (float*)d_out;

  float* ws = (float*)d_ws;
  const size_t NF = (size_t)N * DD;
  float* bufA   = ws;                        // NF fp32 (h even layers; y1 after loop)
  float* bufB   = bufA + NF;                 // NF fp32 (h odd layers; h0 before loop)
  float* h_sum  = bufB + NF;                 // NF
  float* stats  = h_sum + NF;                // 256 enc + 1024 dec
  float* Wt_dec = stats + 1280;              // 64*128
  unsigned short* Wih_hi = (unsigned short*)(Wt_dec + 64*128);
  unsigned short* Wih_lo = Wih_hi + 384*128;
  unsigned short* Whh_hi = Wih_lo + 384*128;
  unsigned short* Whh_lo = Whh_hi + 384*128;
  unsigned short* ph_hi  = Whh_lo + 384*128; // NF ushorts
  unsigned short* ph_lo  = ph_hi + NF;
  int*   counts  = (int*)(ph_lo + NF);       // N
  int*   offsets = counts + N;               // N+1
  int*   cursors = offsets + N + 1;          // N
  int*   partials= cursors + N;              // P
  int*   csr_src = partials + P;             // E
  float* csr_norm = (float*)(csr_src + E);   // E
  float* h0 = bufB;                          // consumed before layer 0 writes bufB
  float* y1 = bufA;                          // written after last read of bufA

  hipMemsetAsync(stats, 0, 1280*sizeof(float), stream);
  hipMemsetAsync(counts, 0, (size_t)N*sizeof(int), stream);

  k_prep<<<(64*128 + 255)/256, 256, 0, stream>>>(W_dec, Wt_dec);
  k_prep_frag<<<(2*384*128 + 255)/256, 256, 0, stream>>>(W_ih, W_hh, Wih_hi, Wih_lo, Whh_hi, Whh_lo);
  k_enc<<<256, 128, 0, stream>>>(x, W_enc, h0, stats, N);
  k_enc_apply<<<(N*DD + 255)/256, 256, 0, stream>>>(h0, g_e, b_e, stats, bufA, h_sum, ph_hi, ph_lo, N);

  k_hist<<<(E + 255)/256, 256, 0, stream>>>(dst, counts, E);
  k_scan_part<<<P, 256, 0, stream>>>(counts, partials, N);
  k_scan_mid<<<1, 256, 0, stream>>>(partials, P, offsets, N);
  k_scan_expand<<<P, 256, 0, stream>>>(counts, partials, offsets, cursors, N);
  k_fill<<<(E + 255)/256, 256, 0, stream>>>(src, dst, norm, cursors, csr_src, csr_norm, E);

  float* cur = bufA;
  float* nxt = bufB;
  for (int l = 0; l < 5; l++){
    k_layer<<<(N + 31)/32, 512, 0, stream>>>(cur, nxt, ph_hi, ph_lo, h_sum,
                                             offsets, csr_src, csr_norm,
                                             Wih_hi, Wih_lo, Whh_hi, Whh_lo, b_ih, b_hh, N);
    float* tmp = cur; cur = nxt; nxt = tmp;
  }

  k_dec1<<<1024, 256, 0, stream>>>(h_sum, Wt_dec, y1, stats + 256, N);
  k_dec2<<<(N + 3)/4, 256, 0, stream>>>(y1, g_d, b_d, W_dec2, stats + 256, out, N);
}